// Round 5
// baseline (248.461 us; speedup 1.0000x reference)
//
#include <hip/hip_runtime.h>
#include <hip/hip_bf16.h>

typedef __bf16 bf16x8 __attribute__((ext_vector_type(8)));
typedef float  f32x4  __attribute__((ext_vector_type(4)));

#define WBT_STRIDE 136   // bf16/row: 80 rows x 128 k (+XOR-swizzled 8-elem k-blocks)
#define H1_STRIDE  104   // bf16/row: 128 rows x 96 k
#define W3T_STRIDE 104   // bf16/row: 48 rows x 96 k

__global__ __launch_bounds__(512, 4)
void attn_fused(const float* __restrict__ query,
                const float* __restrict__ facts,
                const int*   __restrict__ mask,
                const float* __restrict__ W1, const float* __restrict__ b1,
                const float* __restrict__ alpha,
                const float* __restrict__ W2, const float* __restrict__ b2,
                const float* __restrict__ W3, const float* __restrict__ b3,
                const float* __restrict__ W4,
                float* __restrict__ out)
{
    __shared__ __align__(16) __bf16 WbT[80 * WBT_STRIDE];    // folded W2, [n][k-swizzled]
    __shared__ __align__(16) __bf16 W3T[48 * W3T_STRIDE];    // W3^T zero-padded
    __shared__ __align__(16) __bf16 h1all[128 * H1_STRIDE];  // per-wave 16-row slabs
    __shared__ float qy[128], qs[128], qcs[80];
    __shared__ float qpart[4][128], qcp[4][80];
    __shared__ float w4s[48], b3s[48];
    __shared__ float outw[8 * 128];
    __shared__ float Zw[8];

    const int b = blockIdx.x, t = threadIdx.x;
    const int wave = t >> 6, lane = t & 63, qd = lane >> 4, m = lane & 15;
    const float* fb = facts + (size_t)b * (512 * 128);
    const int*   mb = mask + b * 512;

    // ---- issue tile-0 facts loads + all mask loads FIRST (in flight all prologue) ----
    f32x4 av[2][4][2];
    int mv[4];
    {
        const float* p0 = &fb[(size_t)(wave * 64 + m) * 128 + qd * 8];
        #pragma unroll
        for (int kc = 0; kc < 4; ++kc) {
            av[0][kc][0] = *(const f32x4*)(p0 + kc * 32);
            av[0][kc][1] = *(const f32x4*)(p0 + kc * 32 + 4);
        }
        #pragma unroll
        for (int tl = 0; tl < 4; ++tl) mv[tl] = mb[wave * 64 + tl * 16 + m];
    }

    // ---- prologue: query, W3^T, h1 pad cols, small vecs ----
    if (t < 128) qy[t] = query[b * 128 + t];
    for (int e = t; e < 48 * 96; e += 512) {
        int j = e / 96, k = e % 96;                          // W3 row-major [80][40]
        W3T[j * W3T_STRIDE + k] = (j < 40 && k < 80) ? (__bf16)W3[k * 40 + j]
                                                     : (__bf16)0.0f;
    }
    for (int e = t; e < 128 * 16; e += 512) {                // h1 cols 80..95 := 0
        int r = e >> 4, c = 80 + (e & 15);
        h1all[r * H1_STRIDE + c] = (__bf16)0.0f;
    }
    if (t < 48) { w4s[t] = (t < 40) ? W4[t] : 0.f; b3s[t] = (t < 40) ? b3[t] : 0.f; }
    __syncthreads();

    // q = PReLU(query @ W1 + b1), split-K x4
    {
        int j = t & 127, kh = t >> 7;
        float acc = (kh == 0) ? b1[j] : 0.f;
        const float* w1p = W1 + (kh * 32) * 128 + j;
        #pragma unroll 8
        for (int k = 0; k < 32; ++k) acc = fmaf(qy[kh * 32 + k], w1p[k * 128], acc);
        qpart[kh][j] = acc;
    }
    __syncthreads();
    if (t < 128) {
        float s = (qpart[0][t] + qpart[1][t]) + (qpart[2][t] + qpart[3][t]);
        qs[t] = (s >= 0.f) ? s : alpha[t] * s;
    }
    __syncthreads();

    // qconst = q@(W2a+W2c)+b2 (split-K x4); fold WbT[n][k] = W2b - W2c + q_k*W2d
    if (t < 320) {
        int jj = t % 80, hh = t / 80;
        float acc = (hh == 0) ? b2[jj] : 0.f;
        #pragma unroll 8
        for (int k = hh * 32; k < hh * 32 + 32; ++k)
            acc = fmaf(qs[k], W2[k * 80 + jj] + W2[(256 + k) * 80 + jj], acc);
        qcp[hh][jj] = acc;
    }
    for (int e = t; e < 128 * 80; e += 512) {
        int k = e / 80, n = e - k * 80;
        float w = W2[(128 + k) * 80 + n] - W2[(256 + k) * 80 + n]
                + qs[k] * W2[(384 + k) * 80 + n];
        // XOR swizzle: k-block j=k>>3 stored at j^(n&3)  (kills 8-way write conflicts)
        WbT[n * WBT_STRIDE + (((k >> 3) ^ (n & 3)) << 3) + (k & 7)] = (__bf16)w;
    }
    __syncthreads();
    if (t < 80) qcs[t] = (qcp[0][t] + qcp[1][t]) + (qcp[2][t] + qcp[3][t]);
    __syncthreads();

    // ---- main: wave owns rows [64w, 64w+64); 4 tiles, distance-1 pipelined ----
    __bf16* h1w = &h1all[wave * 16 * H1_STRIDE];

    float oacc[4][8];
    #pragma unroll
    for (int kc = 0; kc < 4; ++kc)
        #pragma unroll
        for (int i = 0; i < 8; ++i) oacc[kc][i] = 0.f;
    float Zl = 0.f;
    float pmprev = 0.f;

    #pragma unroll
    for (int tile = 0; tile < 4; ++tile) {
        const int p = tile & 1;

        // deferred accumulate of tile-1's contribution (pm long ready; frees av[1-p])
        if (tile > 0) {
            #pragma unroll
            for (int kc = 0; kc < 4; ++kc)
                #pragma unroll
                for (int i = 0; i < 4; ++i) {
                    oacc[kc][i]     = fmaf(pmprev, av[1 - p][kc][0][i], oacc[kc][i]);
                    oacc[kc][i + 4] = fmaf(pmprev, av[1 - p][kc][1][i], oacc[kc][i + 4]);
                }
            Zl += pmprev;
        }
        // prefetch tile+1 into the freed buffer (in flight through this whole body)
        if (tile < 3) {
            const float* pn = &fb[(size_t)(wave * 64 + (tile + 1) * 16 + m) * 128 + qd * 8];
            #pragma unroll
            for (int kc = 0; kc < 4; ++kc) {
                av[1 - p][kc][0] = *(const f32x4*)(pn + kc * 32);
                av[1 - p][kc][1] = *(const f32x4*)(pn + kc * 32 + 4);
            }
        }

        bf16x8 af[4];
        #pragma unroll
        for (int kc = 0; kc < 4; ++kc)
            #pragma unroll
            for (int i = 0; i < 8; ++i)
                af[kc][i] = (__bf16)((i < 4) ? av[p][kc][0][i] : av[p][kc][1][i - 4]);

        // GEMM1: [16,128]@[128,80] -> sigmoid -> h1 (wave-private LDS slab)
        #pragma unroll
        for (int ct = 0; ct < 5; ++ct) {
            f32x4 acc = {0.f, 0.f, 0.f, 0.f};
            const int n1 = ct * 16 + m;
            #pragma unroll
            for (int kc = 0; kc < 4; ++kc) {
                bf16x8 bfr = *(const bf16x8*)
                    &WbT[n1 * WBT_STRIDE + (((kc * 4 + qd) ^ (m & 3)) << 3)];
                acc = __builtin_amdgcn_mfma_f32_16x16x32_bf16(af[kc], bfr, acc, 0, 0, 0);
            }
            const float qc = qcs[n1];
            #pragma unroll
            for (int r = 0; r < 4; ++r) {
                float x = acc[r] + qc;
                float h = __builtin_amdgcn_rcpf(1.0f + __expf(-x));
                h1w[(qd * 4 + r) * H1_STRIDE + n1] = (__bf16)h;
            }
        }
        asm volatile("s_waitcnt lgkmcnt(0)" ::: "memory");   // wave-private: no barrier

        // GEMM2: [16,96]@[96,48] -> sigmoid -> score = h2 @ W4
        bf16x8 a2[3];
        #pragma unroll
        for (int kc = 0; kc < 3; ++kc)
            a2[kc] = *(const bf16x8*)&h1w[m * H1_STRIDE + kc * 32 + qd * 8];
        float sc[4] = {0.f, 0.f, 0.f, 0.f};
        #pragma unroll
        for (int ct = 0; ct < 3; ++ct) {
            f32x4 acc2 = {0.f, 0.f, 0.f, 0.f};
            #pragma unroll
            for (int kc = 0; kc < 3; ++kc) {
                bf16x8 bfr = *(const bf16x8*)&W3T[(ct * 16 + m) * W3T_STRIDE + kc * 32 + qd * 8];
                acc2 = __builtin_amdgcn_mfma_f32_16x16x32_bf16(a2[kc], bfr, acc2, 0, 0, 0);
            }
            const int col = ct * 16 + m;
            const float w4v = w4s[col], b3v = b3s[col];
            #pragma unroll
            for (int r = 0; r < 4; ++r) {
                float h2 = __builtin_amdgcn_rcpf(1.0f + __expf(-(acc2[r] + b3v)));
                sc[r] = fmaf(h2, w4v, sc[r]);
            }
        }
        #pragma unroll
        for (int d = 1; d < 16; d <<= 1)
            #pragma unroll
            for (int r = 0; r < 4; ++r)
                sc[r] += __shfl_xor(sc[r], d);

        // own-row score via bpermute (row m lives as sc[m&3] in quad m>>2)
        const int idx = ((((m >> 2) << 4) | m) << 2);
        float s0v = __int_as_float(__builtin_amdgcn_ds_bpermute(idx, __float_as_int(sc[0])));
        float s1v = __int_as_float(__builtin_amdgcn_ds_bpermute(idx, __float_as_int(sc[1])));
        float s2v = __int_as_float(__builtin_amdgcn_ds_bpermute(idx, __float_as_int(sc[2])));
        float s3v = __int_as_float(__builtin_amdgcn_ds_bpermute(idx, __float_as_int(sc[3])));
        const int rr = m & 3;
        float srow = (rr == 0) ? s0v : (rr == 1) ? s1v : (rr == 2) ? s2v : s3v;

        // p = mask ? exp(score) : 0  (|score| <= sum|W4| ~ 5; b4 cancels in softmax)
        pmprev = (mv[tile] == 1) ? __expf(srow) : 0.f;
    }
    // final accumulate (tile 3 lives in av[1])
    #pragma unroll
    for (int kc = 0; kc < 4; ++kc)
        #pragma unroll
        for (int i = 0; i < 4; ++i) {
            oacc[kc][i]     = fmaf(pmprev, av[1][kc][0][i], oacc[kc][i]);
            oacc[kc][i + 4] = fmaf(pmprev, av[1][kc][1][i], oacc[kc][i + 4]);
        }
    Zl += pmprev;

    // ---- epilogue: reduce over m, combine 8 waves, normalize ----
    #pragma unroll
    for (int d = 1; d < 16; d <<= 1) {
        #pragma unroll
        for (int kc = 0; kc < 4; ++kc)
            #pragma unroll
            for (int i = 0; i < 8; ++i)
                oacc[kc][i] += __shfl_xor(oacc[kc][i], d);
        Zl += __shfl_xor(Zl, d);
    }
    if (m == 0) {
        #pragma unroll
        for (int kc = 0; kc < 4; ++kc)
            #pragma unroll
            for (int i = 0; i < 8; ++i)
                outw[wave * 128 + kc * 32 + qd * 8 + i] = oacc[kc][i];
        if (lane == 0) Zw[wave] = Zl;
    }
    __syncthreads();

    if (t < 128) {
        float v = 0.f, Z = 0.f;
        #pragma unroll
        for (int w = 0; w < 8; ++w) { v += outw[w * 128 + t]; Z += Zw[w]; }
        out[b * 128 + t] = v / Z;
    }
}

extern "C" void kernel_launch(void* const* d_in, const int* in_sizes, int n_in,
                              void* d_out, int out_size, void* d_ws, size_t ws_size,
                              hipStream_t stream) {
    (void)in_sizes; (void)n_in; (void)d_ws; (void)ws_size; (void)out_size;
    const float* query = (const float*)d_in[0];
    const float* facts = (const float*)d_in[1];
    const int*   mask  = (const int*)d_in[2];
    const float* W1 = (const float*)d_in[3];
    const float* b1 = (const float*)d_in[4];
    const float* al = (const float*)d_in[5];
    const float* W2 = (const float*)d_in[6];
    const float* b2 = (const float*)d_in[7];
    const float* W3 = (const float*)d_in[8];
    const float* b3 = (const float*)d_in[9];
    const float* W4 = (const float*)d_in[10];
    const float* b4 = (const float*)d_in[11];
    (void)b4;  // cancels under softmax
    attn_fused<<<dim3(512), dim3(512), 0, stream>>>(
        query, facts, mask, W1, b1, al, W2, b2, W3, b3, W4, (float*)d_out);
}